// Round 9
// baseline (386.822 us; speedup 1.0000x reference)
//
#include <hip/hip_runtime.h>

typedef __bf16 bf16_t;
typedef __bf16 bf16x8 __attribute__((ext_vector_type(8)));
typedef float f32x4 __attribute__((ext_vector_type(4)));
typedef float f32x16 __attribute__((ext_vector_type(16)));
typedef unsigned short u16;
typedef unsigned int u32;

#define NTOK 1025
#define MTOT 8200
#define MPAD 8448
#define CDIM 768

__device__ __forceinline__ u16 f2bf(float f) {
  union { float f; unsigned u; } v; v.f = f;
  unsigned r = v.u + 0x7fffu + ((v.u >> 16) & 1u);
  return (u16)(r >> 16);
}
__device__ __forceinline__ float bf2f(u16 h) {
  union { unsigned u; float f; } v; v.u = ((unsigned)h) << 16; return v.f;
}
__device__ __forceinline__ u32 cvtpk(float lo, float hi) {
  u32 r; asm("v_cvt_pk_bf16_f32 %0, %1, %2" : "=v"(r) : "v"(lo), "v"(hi)); return r;
}
__device__ __forceinline__ void gld16(const void* g, void* l) {
  __builtin_amdgcn_global_load_lds(
      (const __attribute__((address_space(1))) unsigned*)g,
      (__attribute__((address_space(3))) unsigned*)l, 16, 0, 0);
}

// ---------------- K0a: fp32 -> bf16 convert ----------------
__global__ void conv_x(const float4* __restrict__ in, u16* __restrict__ out, int n4) {
  int i = blockIdx.x * blockDim.x + threadIdx.x;
  if (i < n4) {
    float4 f = in[i];
    ushort4 o; o.x = f2bf(f.x); o.y = f2bf(f.y); o.z = f2bf(f.z); o.w = f2bf(f.w);
    *(ushort4*)&out[i * 4] = o;
  }
}

// ---------------- K0b: transpose-convert  in[K][N] fp32 -> out[N][K] bf16 ----------------
__global__ __launch_bounds__(256) void transp(const float* __restrict__ in,
                                              u16* __restrict__ out, int K, int N) {
  __shared__ float tile[32][33];
  int n0 = blockIdx.x * 32, k0 = blockIdx.y * 32;
  int tx = threadIdx.x & 31, ty = threadIdx.x >> 5;
#pragma unroll
  for (int i = 0; i < 4; ++i)
    tile[ty + i * 8][tx] = in[(k0 + ty + i * 8) * N + n0 + tx];
  __syncthreads();
#pragma unroll
  for (int i = 0; i < 4; ++i)
    out[(n0 + ty + i * 8) * K + k0 + tx] = f2bf(tile[tx][ty + i * 8]);
}

// ---------------- shared 128x128 K-loop (single-buffer, swizzled, r4-proven) ----------------
template <bool TRANS>
__device__ __forceinline__ void kloop128(const u16* __restrict__ A, const u16* __restrict__ Bt,
                                         int m0, int n0, u16* As, u16* Bs, int t,
                                         f32x4 (*acc)[4]) {
  const int K = 768;
  int lane = t & 63, wave = t >> 6;
  int ln = lane & 15, hi = lane >> 4;
  int wr = wave >> 1, wc = wave & 1;
  int swz = (ln & 7) << 4;
  int trow = t >> 3;
  int tcolb = (t & 7) * 16;
  int scol = ((tcolb ^ ((trow & 7) << 4)) >> 1);

  for (int k0 = 0; k0 < K; k0 += 64) {
#pragma unroll
    for (int c = 0; c < 4; ++c) {
      gld16(&A[(size_t)(m0 + c * 32 + trow) * K + k0 + scol], &As[c * 2048 + t * 8]);
      gld16(&Bt[(size_t)(n0 + c * 32 + trow) * K + k0 + scol], &Bs[c * 2048 + t * 8]);
    }
    asm volatile("s_waitcnt vmcnt(0)" ::: "memory");
    __builtin_amdgcn_s_barrier();
    asm volatile("" ::: "memory");
#pragma unroll
    for (int kk = 0; kk < 2; ++kk) {
      bf16x8 af[4], bfr[4];
#pragma unroll
      for (int i = 0; i < 4; ++i)
        af[i] = *(const bf16x8*)((const char*)&As[(wr * 64 + i * 16 + ln) * 64]
                                 + ((kk * 64 + hi * 16) ^ swz));
#pragma unroll
      for (int j = 0; j < 4; ++j)
        bfr[j] = *(const bf16x8*)((const char*)&Bs[(wc * 64 + j * 16 + ln) * 64]
                                  + ((kk * 64 + hi * 16) ^ swz));
      __builtin_amdgcn_s_setprio(1);
#pragma unroll
      for (int x = 0; x < 4; ++x)
#pragma unroll
        for (int y = 0; y < 4; ++y)
          acc[x][y] = TRANS
              ? __builtin_amdgcn_mfma_f32_16x16x32_bf16(bfr[x], af[y], acc[x][y], 0, 0, 0)
              : __builtin_amdgcn_mfma_f32_16x16x32_bf16(af[x], bfr[y], acc[x][y], 0, 0, 0);
      __builtin_amdgcn_s_setprio(0);
    }
    asm volatile("" ::: "memory");
    __builtin_amdgcn_s_barrier();
  }
}

// ---------------- K1a: QKV GEMM for q/k cols (transposed frags) + bias + RoPE fused ----------------
__global__ __launch_bounds__(256) void qkv_gemm_t(
    const u16* __restrict__ A, const u16* __restrict__ Bt,
    const float* __restrict__ qbias, const float* __restrict__ rope,
    u16* __restrict__ q, u16* __restrict__ k) {
  const int NB = 12;
  __shared__ u16 As[8192], Bs[8192];
  int tau0 = blockIdx.x;
  int xcd = tau0 & 7, pos = tau0 >> 3;
  int tau = (xcd < 4) ? xcd * 98 + pos : 392 + (xcd - 4) * 97 + pos;
  int bx = tau % NB, by = tau / NB;
  int m0 = by * 128, n0 = bx * 128;
  int t = threadIdx.x;
  int lane = t & 63, wave = t >> 6;
  int ln = lane & 15, hi = lane >> 4;
  int wr = wave >> 1, wc = wave & 1;

  f32x4 acc[4][4] = {};
  kloop128<true>(A, Bt, m0, n0, As, Bs, t, acc);

  const float scale = 0.125f * 1.4426950408889634f;
#pragma unroll
  for (int ii = 0; ii < 4; ++ii) {
    int m = m0 + wr * 64 + ii * 16 + ln;
    if (m < MTOT) {
      int b = m / NTOK;
      int n = m - b * NTOK;
      const float* rp = rope + (size_t)(n - 1) * 128;
#pragma unroll
      for (int jj = 0; jj < 4; ++jj) {
        int c4 = n0 + wc * 64 + jj * 16 + hi * 4;
        int part = (c4 >= CDIM) ? 1 : 0;
        int cc = c4 - part * CDIM;
        int h = cc >> 6, d4 = cc & 63;
        float v0 = acc[jj][ii][0], v1 = acc[jj][ii][1];
        float v2 = acc[jj][ii][2], v3 = acc[jj][ii][3];
        if (part == 0) {
          float4 qb = *(const float4*)(qbias + cc);
          v0 += qb.x; v1 += qb.y; v2 += qb.z; v3 += qb.w;
        }
        float o0, o1, o2, o3;
        if (n > 0) {
          float4 sn = *(const float4*)(rp + d4);
          float4 cs = *(const float4*)(rp + 64 + d4);
          o0 = v0 * cs.x - v1 * sn.x;
          o1 = v1 * cs.y + v0 * sn.y;
          o2 = v2 * cs.z - v3 * sn.z;
          o3 = v3 * cs.w + v2 * sn.w;
        } else { o0 = v0; o1 = v1; o2 = v2; o3 = v3; }
        if (part == 0) { o0 *= scale; o1 *= scale; o2 *= scale; o3 *= scale; }
        uint2 w; w.x = cvtpk(o0, o1); w.y = cvtpk(o2, o3);
        u16* dst = (part ? k : q) + ((size_t)(h * MPAD + m)) * 64 + d4;
        *(uint2*)dst = w;
      }
    }
  }
}

// ---------------- K1b: QKV GEMM for v cols (normal frags) + bias -> vt [12][64][MPAD] ----------------
__global__ __launch_bounds__(256) void qkv_gemm_v(
    const u16* __restrict__ A, const u16* __restrict__ Bt,
    const float* __restrict__ vbias, u16* __restrict__ vt) {
  const int NB = 6;
  __shared__ u16 As[8192], Bs[8192];
  int tau0 = blockIdx.x;
  int xcd = tau0 & 7, pos = tau0 >> 3;
  int tau = (xcd < 6) ? xcd * 49 + pos : 294 + (xcd - 6) * 48 + pos;
  int bx = tau % NB, by = tau / NB;
  int m0 = by * 128, n0 = 1536 + bx * 128;
  int t = threadIdx.x;
  int lane = t & 63, wave = t >> 6;
  int ln = lane & 15, hi = lane >> 4;
  int wr = wave >> 1, wc = wave & 1;

  f32x4 acc[4][4] = {};
  kloop128<false>(A, Bt, m0, n0, As, Bs, t, acc);

#pragma unroll
  for (int i = 0; i < 4; ++i) {
    int mrow = m0 + wr * 64 + i * 16 + hi * 4;
    if (mrow < MTOT) {
      bool full = (mrow + 3 < MTOT);
#pragma unroll
      for (int j = 0; j < 4; ++j) {
        int cv = n0 - 1536 + wc * 64 + j * 16 + ln;
        int h = cv >> 6, d = cv & 63;
        float vb = vbias[cv];
        float v0 = acc[i][j][0] + vb, v1 = acc[i][j][1] + vb;
        float v2 = acc[i][j][2] + vb, v3 = acc[i][j][3] + vb;
        u16* dst = vt + ((size_t)(h * 64 + d)) * MPAD + mrow;
        if (full) {
          uint2 w; w.x = cvtpk(v0, v1); w.y = cvtpk(v2, v3);
          *(uint2*)dst = w;
        } else {
          float vv[4] = {v0, v1, v2, v3};
#pragma unroll
          for (int r = 0; r < 4; ++r)
            if (mrow + r < MTOT) dst[r] = f2bf(vv[r]);
        }
      }
    }
  }
}

// ---------------- K3: flash attention — barrier-free, LDS-free, L2-direct K/V ----------------
// q,k: [12][MPAD][64] ; vt: [12][64][MPAD] ; y: [8200][768] bf16
__global__ __launch_bounds__(256) void flash_attn(
    const u16* __restrict__ q, const u16* __restrict__ k,
    const u16* __restrict__ vt, u16* __restrict__ y) {
  int f = blockIdx.x;                 // 864 = 8 XCD-chunks * 108
  int xcd = f & 7, idx = f >> 3;
  int bh = xcd * 12 + idx / 9;
  int qt = idx - (idx / 9) * 9;
  int b = bh / 12, h = bh - b * 12;
  int t = threadIdx.x, lane = t & 63, w = t >> 6;
  int lq = lane & 31, h2 = lane >> 5;
  int q0 = qt * 128 + w * 32;
  if (q0 >= NTOK) return;             // wave-uniform; no barriers in this kernel
  int qrow = q0 + lq; if (qrow > NTOK - 1) qrow = NTOK - 1;

  const size_t kbase = ((size_t)h * MPAD + (size_t)b * NTOK) * 64;
  const size_t vbase = (size_t)h * 64 * MPAD + (size_t)b * NTOK;

  const u16* qp = q + kbase + (size_t)qrow * 64;
  bf16x8 qf[4];
#pragma unroll
  for (int s = 0; s < 4; ++s)
    qf[s] = *(const bf16x8*)&qp[s * 16 + h2 * 8];

  f32x16 acc[2] = {};
  float l = 0.f;

  for (int it = 0; it < 17; ++it) {
    int kt = it * 64;
    // ---- QK^T (swapped): S^T[key][q], K fragments straight from L2 ----
    f32x16 sc[2] = {};
    __builtin_amdgcn_s_setprio(1);
#pragma unroll
    for (int c = 0; c < 2; ++c) {
      const u16* kr = k + kbase + (size_t)(kt + c * 32 + lq) * 64 + h2 * 8;
#pragma unroll
      for (int s = 0; s < 4; ++s) {
        bf16x8 kf = *(const bf16x8*)&kr[s * 16];
        sc[c] = __builtin_amdgcn_mfma_f32_32x32x16_bf16(kf, qf[s], sc[c], 0, 0, 0);
      }
    }
    __builtin_amdgcn_s_setprio(0);
    // ---- no-max softmax: p = exp2(s) ----
    float p[2][16];
#pragma unroll
    for (int c = 0; c < 2; ++c)
#pragma unroll
      for (int r = 0; r < 16; ++r)
        p[c][r] = __builtin_amdgcn_exp2f(sc[c][r]);
    if (it == 16) {                   // zero padded keys (>=1025); overrides garbage
#pragma unroll
      for (int c = 0; c < 2; ++c)
#pragma unroll
        for (int r = 0; r < 16; ++r) {
          int kk = kt + c * 32 + (r & 3) + 8 * (r >> 2) + 4 * h2;
          if (kk >= NTOK) p[c][r] = 0.f;
        }
    }
    float rs = 0.f;
#pragma unroll
    for (int c = 0; c < 2; ++c)
#pragma unroll
      for (int r = 0; r < 16; ++r) rs += p[c][r];
    l += rs;
    // ---- P -> bf16 B-fragments via cvt_pk + v_permlane32_swap_b32 ----
    // ISA: swap(dst,src): dst.row1 <-> src.row0  =>  dst' = {dst_lo, src_lo},
    //                                                src' = {dst_hi, src_hi}.
    // dst = LOW-key reg (pk[2i]), src = pk[2i+1 pair partner] (pk[2i+? +2]):
    //   swap(k0,k2): k0 -> w0 = {own keys0-1 | partner keys8-9}
    //                k2 -> w2 = {partner keys4-5 | own keys12-13}
    bf16x8 frag[4];
#pragma unroll
    for (int c = 0; c < 2; ++c) {
      u32 k0 = cvtpk(p[c][0], p[c][1]),  k1 = cvtpk(p[c][2], p[c][3]);
      u32 k2 = cvtpk(p[c][4], p[c][5]),  k3 = cvtpk(p[c][6], p[c][7]);
      u32 k4 = cvtpk(p[c][8], p[c][9]),  k5 = cvtpk(p[c][10], p[c][11]);
      u32 k6 = cvtpk(p[c][12], p[c][13]), k7 = cvtpk(p[c][14], p[c][15]);
      asm("v_permlane32_swap_b32 %0, %1" : "+v"(k0), "+v"(k2));
      asm("v_permlane32_swap_b32 %0, %1" : "+v"(k1), "+v"(k3));
      asm("v_permlane32_swap_b32 %0, %1" : "+v"(k4), "+v"(k6));
      asm("v_permlane32_swap_b32 %0, %1" : "+v"(k5), "+v"(k7));
      union { u32 u[4]; bf16x8 v; } u0, u1;
      u0.u[0] = k0; u0.u[1] = k1; u0.u[2] = k2; u0.u[3] = k3;
      u1.u[0] = k4; u1.u[1] = k5; u1.u[2] = k6; u1.u[3] = k7;
      frag[c * 2] = u0.v; frag[c * 2 + 1] = u1.v;
    }
    // ---- PV (swapped): Y^T[d][q] += V^T x P, V fragments straight from L2 ----
    __builtin_amdgcn_s_setprio(1);
#pragma unroll
    for (int hf = 0; hf < 2; ++hf) {
      const u16* vr = vt + vbase + (size_t)(hf * 32 + lq) * MPAD + kt + h2 * 8;
#pragma unroll
      for (int s = 0; s < 4; ++s) {
        bf16x8 vf = *(const bf16x8*)&vr[s * 16];
        acc[hf] = __builtin_amdgcn_mfma_f32_32x32x16_bf16(vf, frag[s], acc[hf], 0, 0, 0);
      }
    }
    __builtin_amdgcn_s_setprio(0);
  }

  int row = q0 + lq;
  if (row < NTOK) {
    float lt = l + __shfl_xor(l, 32, 64);
    float inv = 1.f / lt;
    u16* yr = y + ((size_t)(b * NTOK + row)) * CDIM + h * 64;
#pragma unroll
    for (int hf = 0; hf < 2; ++hf)
#pragma unroll
      for (int g = 0; g < 4; ++g) {
        int d0 = hf * 32 + 8 * g + 4 * h2;
        ushort4 o;
        o.x = f2bf(acc[hf][g * 4 + 0] * inv);
        o.y = f2bf(acc[hf][g * 4 + 1] * inv);
        o.z = f2bf(acc[hf][g * 4 + 2] * inv);
        o.w = f2bf(acc[hf][g * 4 + 3] * inv);
        *(ushort4*)&yr[d0] = o;
      }
  }
}

// ---------------- K4: LayerNorm (bf16 in) -> bf16 ----------------
__global__ __launch_bounds__(256) void lnorm(const u16* __restrict__ y,
                                             const float* __restrict__ gamma,
                                             const float* __restrict__ beta,
                                             u16* __restrict__ out) {
  int row = blockIdx.x;
  const u16* yr = y + (size_t)row * CDIM;
  int t = threadIdx.x;
  float v[3];
  float s = 0.f, s2 = 0.f;
#pragma unroll
  for (int i = 0; i < 3; ++i) {
    v[i] = bf2f(yr[t + 256 * i]);
    s += v[i]; s2 += v[i] * v[i];
  }
#pragma unroll
  for (int msk = 1; msk < 64; msk <<= 1) {
    s  += __shfl_xor(s, msk, 64);
    s2 += __shfl_xor(s2, msk, 64);
  }
  __shared__ float ws[8];
  int w = t >> 6, lane = t & 63;
  if (lane == 0) { ws[w] = s; ws[4 + w] = s2; }
  __syncthreads();
  s = ws[0] + ws[1] + ws[2] + ws[3];
  s2 = ws[4] + ws[5] + ws[6] + ws[7];
  float mu = s * (1.f / 768.f);
  float var = s2 * (1.f / 768.f) - mu * mu;
  float rstd = rsqrtf(var + 1e-6f);
#pragma unroll
  for (int i = 0; i < 3; ++i) {
    int c = t + 256 * i;
    out[(size_t)row * CDIM + c] = f2bf((v[i] - mu) * rstd * gamma[c] + beta[c]);
  }
}

// ---------------- K5: proj GEMM (transposed frags) + bias -> fp32, float4 stores ----------------
__global__ __launch_bounds__(256) void proj_gemm(
    const u16* __restrict__ A, const u16* __restrict__ Bt,
    const float* __restrict__ bias, float* __restrict__ out) {
  const int NB = 6;
  __shared__ u16 As[8192], Bs[8192];
  int tau0 = blockIdx.x;
  int xcd = tau0 & 7, pos = tau0 >> 3;
  int tau = (xcd < 6) ? xcd * 49 + pos : 294 + (xcd - 6) * 48 + pos;
  int bx = tau % NB, by = tau / NB;
  int m0 = by * 128, n0 = bx * 128;
  int t = threadIdx.x;
  int lane = t & 63, wave = t >> 6;
  int ln = lane & 15, hi = lane >> 4;
  int wr = wave >> 1, wc = wave & 1;

  f32x4 acc[4][4] = {};
  kloop128<true>(A, Bt, m0, n0, As, Bs, t, acc);

#pragma unroll
  for (int ii = 0; ii < 4; ++ii) {
    int m = m0 + wr * 64 + ii * 16 + ln;
    if (m < MTOT) {
      float* dr = out + (size_t)m * CDIM;
#pragma unroll
      for (int jj = 0; jj < 4; ++jj) {
        int c4 = n0 + wc * 64 + jj * 16 + hi * 4;
        float4 bv = *(const float4*)(bias + c4);
        float4 o;
        o.x = acc[jj][ii][0] + bv.x;
        o.y = acc[jj][ii][1] + bv.y;
        o.z = acc[jj][ii][2] + bv.z;
        o.w = acc[jj][ii][3] + bv.w;
        *(float4*)(dr + c4) = o;
      }
    }
  }
}

extern "C" void kernel_launch(void* const* d_in, const int* in_sizes, int n_in,
                              void* d_out, int out_size, void* d_ws, size_t ws_size,
                              hipStream_t stream) {
  const float* x      = (const float*)d_in[0];
  const float* rope   = (const float*)d_in[1];
  const float* w_qkv  = (const float*)d_in[2];
  const float* q_bias = (const float*)d_in[3];
  const float* v_bias = (const float*)d_in[4];
  const float* gamma  = (const float*)d_in[5];
  const float* beta   = (const float*)d_in[6];
  const float* w_proj = (const float*)d_in[7];
  const float* b_proj = (const float*)d_in[8];
  float* out = (float*)d_out;

  // Workspace (56.6 MB):
  //  A [0, 12.98M):        xb -> ybf
  //  [12.98M, 16.52M):     wqkvt
  //  [16.52M, 17.69M):     wprjt
  //  B [17.69M, 30.67M):   qbuf [12][8448][64] -> ylb
  //  [30.67M, 43.65M):     kbuf [12][8448][64]
  //  [43.65M, 56.62M):     vtg  [12][64][8448]
  char* ws = (char*)d_ws;
  u16* xb    = (u16*)(ws);
  u16* ybf   = (u16*)(ws);
  u16* wqkvt = (u16*)(ws + 12976128);
  u16* wprjt = (u16*)(ws + 16515072);
  u16* qbuf  = (u16*)(ws + 17694720);
  u16* ylb   = (u16*)(ws + 17694720);
  u16* kbuf  = (u16*)(ws + 30670848);
  u16* vtg   = (u16*)(ws + 43646976);

  conv_x<<<(1574400 + 255) / 256, 256, 0, stream>>>((const float4*)x, xb, 1574400);
  transp<<<dim3(2304 / 32, 768 / 32), 256, 0, stream>>>(w_qkv, wqkvt, 768, 2304);
  transp<<<dim3(768 / 32, 768 / 32), 256, 0, stream>>>(w_proj, wprjt, 768, 768);

  qkv_gemm_t<<<dim3(780), 256, 0, stream>>>(xb, wqkvt, q_bias, rope, qbuf, kbuf);
  qkv_gemm_v<<<dim3(390), 256, 0, stream>>>(xb, wqkvt, v_bias, vtg);
  flash_attn<<<dim3(864), 256, 0, stream>>>(qbuf, kbuf, vtg, ybf);
  lnorm<<<8200, 256, 0, stream>>>(ybf, gamma, beta, ylb);
  proj_gemm<<<dim3(390), 256, 0, stream>>>(ylb, wprjt, b_proj, out);
}

// Round 10
// 203.624 us; speedup vs baseline: 1.8997x; 1.8997x over previous
//
#include <hip/hip_runtime.h>

typedef __bf16 bf16_t;
typedef __bf16 bf16x8 __attribute__((ext_vector_type(8)));
typedef float f32x4 __attribute__((ext_vector_type(4)));
typedef float f32x16 __attribute__((ext_vector_type(16)));
typedef unsigned short u16;
typedef unsigned int u32;

#define NTOK 1025
#define MTOT 8200
#define MPAD 8448
#define CDIM 768

__device__ __forceinline__ u16 f2bf(float f) {
  union { float f; unsigned u; } v; v.f = f;
  unsigned r = v.u + 0x7fffu + ((v.u >> 16) & 1u);
  return (u16)(r >> 16);
}
__device__ __forceinline__ float bf2f(u16 h) {
  union { unsigned u; float f; } v; v.u = ((unsigned)h) << 16; return v.f;
}
__device__ __forceinline__ u32 cvtpk(float lo, float hi) {
  u32 r; asm("v_cvt_pk_bf16_f32 %0, %1, %2" : "=v"(r) : "v"(lo), "v"(hi)); return r;
}
__device__ __forceinline__ void gld16(const void* g, void* l) {
  __builtin_amdgcn_global_load_lds(
      (const __attribute__((address_space(1))) unsigned*)g,
      (__attribute__((address_space(3))) unsigned*)l, 16, 0, 0);
}

// ---------------- K0a: fp32 -> bf16 convert ----------------
__global__ void conv_x(const float4* __restrict__ in, u16* __restrict__ out, int n4) {
  int i = blockIdx.x * blockDim.x + threadIdx.x;
  if (i < n4) {
    float4 f = in[i];
    ushort4 o; o.x = f2bf(f.x); o.y = f2bf(f.y); o.z = f2bf(f.z); o.w = f2bf(f.w);
    *(ushort4*)&out[i * 4] = o;
  }
}

// ---------------- K0b: transpose-convert  in[K][N] fp32 -> out[N][K] bf16 ----------------
__global__ __launch_bounds__(256) void transp(const float* __restrict__ in,
                                              u16* __restrict__ out, int K, int N) {
  __shared__ float tile[32][33];
  int n0 = blockIdx.x * 32, k0 = blockIdx.y * 32;
  int tx = threadIdx.x & 31, ty = threadIdx.x >> 5;
#pragma unroll
  for (int i = 0; i < 4; ++i)
    tile[ty + i * 8][tx] = in[(k0 + ty + i * 8) * N + n0 + tx];
  __syncthreads();
#pragma unroll
  for (int i = 0; i < 4; ++i)
    out[(n0 + ty + i * 8) * K + k0 + tx] = f2bf(tile[tx][ty + i * 8]);
}

// ---------------- shared 128x128 K-loop (single-buffer, swizzled, r4-proven) ----------------
template <bool TRANS>
__device__ __forceinline__ void kloop128(const u16* __restrict__ A, const u16* __restrict__ Bt,
                                         int m0, int n0, u16* As, u16* Bs, int t,
                                         f32x4 (*acc)[4]) {
  const int K = 768;
  int lane = t & 63, wave = t >> 6;
  int ln = lane & 15, hi = lane >> 4;
  int wr = wave >> 1, wc = wave & 1;
  int swz = (ln & 7) << 4;
  int trow = t >> 3;
  int tcolb = (t & 7) * 16;
  int scol = ((tcolb ^ ((trow & 7) << 4)) >> 1);

  for (int k0 = 0; k0 < K; k0 += 64) {
#pragma unroll
    for (int c = 0; c < 4; ++c) {
      gld16(&A[(size_t)(m0 + c * 32 + trow) * K + k0 + scol], &As[c * 2048 + t * 8]);
      gld16(&Bt[(size_t)(n0 + c * 32 + trow) * K + k0 + scol], &Bs[c * 2048 + t * 8]);
    }
    asm volatile("s_waitcnt vmcnt(0)" ::: "memory");
    __builtin_amdgcn_s_barrier();
    asm volatile("" ::: "memory");
#pragma unroll
    for (int kk = 0; kk < 2; ++kk) {
      bf16x8 af[4], bfr[4];
#pragma unroll
      for (int i = 0; i < 4; ++i)
        af[i] = *(const bf16x8*)((const char*)&As[(wr * 64 + i * 16 + ln) * 64]
                                 + ((kk * 64 + hi * 16) ^ swz));
#pragma unroll
      for (int j = 0; j < 4; ++j)
        bfr[j] = *(const bf16x8*)((const char*)&Bs[(wc * 64 + j * 16 + ln) * 64]
                                  + ((kk * 64 + hi * 16) ^ swz));
      __builtin_amdgcn_s_setprio(1);
#pragma unroll
      for (int x = 0; x < 4; ++x)
#pragma unroll
        for (int y = 0; y < 4; ++y)
          acc[x][y] = TRANS
              ? __builtin_amdgcn_mfma_f32_16x16x32_bf16(bfr[x], af[y], acc[x][y], 0, 0, 0)
              : __builtin_amdgcn_mfma_f32_16x16x32_bf16(af[x], bfr[y], acc[x][y], 0, 0, 0);
      __builtin_amdgcn_s_setprio(0);
    }
    asm volatile("" ::: "memory");
    __builtin_amdgcn_s_barrier();
  }
}

// ---------------- K1a: QKV GEMM q/k cols + bias + RoPE; q plain, k -> fragment layout ----------------
// q: [12][MPAD][64] ; kfrag: [h*8+b][34 tiles][4 s][64 lane][8]
__global__ __launch_bounds__(256) void qkv_gemm_t(
    const u16* __restrict__ A, const u16* __restrict__ Bt,
    const float* __restrict__ qbias, const float* __restrict__ rope,
    u16* __restrict__ q, u16* __restrict__ kfr) {
  const int NB = 12;
  __shared__ u16 As[8192], Bs[8192];
  int tau0 = blockIdx.x;
  int xcd = tau0 & 7, pos = tau0 >> 3;
  int tau = (xcd < 4) ? xcd * 98 + pos : 392 + (xcd - 4) * 97 + pos;
  int bx = tau % NB, by = tau / NB;
  int m0 = by * 128, n0 = bx * 128;
  int t = threadIdx.x;
  int lane = t & 63, wave = t >> 6;
  int ln = lane & 15, hi = lane >> 4;
  int wr = wave >> 1, wc = wave & 1;

  f32x4 acc[4][4] = {};
  kloop128<true>(A, Bt, m0, n0, As, Bs, t, acc);

  const float scale = 0.125f * 1.4426950408889634f;
#pragma unroll
  for (int ii = 0; ii < 4; ++ii) {
    int m = m0 + wr * 64 + ii * 16 + ln;
    if (m < MTOT) {
      int b = m / NTOK;
      int n = m - b * NTOK;
      const float* rp = rope + (size_t)(n - 1) * 128;
#pragma unroll
      for (int jj = 0; jj < 4; ++jj) {
        int c4 = n0 + wc * 64 + jj * 16 + hi * 4;
        int part = (c4 >= CDIM) ? 1 : 0;
        int cc = c4 - part * CDIM;
        int h = cc >> 6, d4 = cc & 63;
        float v0 = acc[jj][ii][0], v1 = acc[jj][ii][1];
        float v2 = acc[jj][ii][2], v3 = acc[jj][ii][3];
        if (part == 0) {
          float4 qb = *(const float4*)(qbias + cc);
          v0 += qb.x; v1 += qb.y; v2 += qb.z; v3 += qb.w;
        }
        float o0, o1, o2, o3;
        if (n > 0) {
          float4 sn = *(const float4*)(rp + d4);
          float4 cs = *(const float4*)(rp + 64 + d4);
          o0 = v0 * cs.x - v1 * sn.x;
          o1 = v1 * cs.y + v0 * sn.y;
          o2 = v2 * cs.z - v3 * sn.z;
          o3 = v3 * cs.w + v2 * sn.w;
        } else { o0 = v0; o1 = v1; o2 = v2; o3 = v3; }
        uint2 w;
        if (part == 0) {
          w.x = cvtpk(o0 * scale, o1 * scale); w.y = cvtpk(o2 * scale, o3 * scale);
          *(uint2*)(q + ((size_t)(h * MPAD + m)) * 64 + d4) = w;
        } else {
          w.x = cvtpk(o0, o1); w.y = cvtpk(o2, o3);
          // fragment-ready scatter: tile = n>>5, lane slot = ((d4>>3)&1)*32 + (n&31)
          int kt2 = n >> 5, lqn = n & 31;
          int sF = d4 >> 4, h2d = (d4 >> 3) & 1, j0 = d4 & 7;
          u16* dst = kfr + ((((size_t)(h * 8 + b) * 34 + kt2) * 4 + sF) * 64
                            + h2d * 32 + lqn) * 8 + j0;
          *(uint2*)dst = w;   // j0 in {0,4} -> 8B aligned
        }
      }
    }
  }
}

// ---------------- K1b: QKV GEMM v cols + bias -> V fragment layout ----------------
// vfrag: [h*8+b][17 tiles][4 s][2 hf][64 lane][8]
__global__ __launch_bounds__(256) void qkv_gemm_v(
    const u16* __restrict__ A, const u16* __restrict__ Bt,
    const float* __restrict__ vbias, u16* __restrict__ vfr) {
  const int NB = 6;
  __shared__ u16 As[8192], Bs[8192];
  int tau0 = blockIdx.x;
  int xcd = tau0 & 7, pos = tau0 >> 3;
  int tau = (xcd < 6) ? xcd * 49 + pos : 294 + (xcd - 6) * 48 + pos;
  int bx = tau % NB, by = tau / NB;
  int m0 = by * 128, n0 = 1536 + bx * 128;
  int t = threadIdx.x;
  int lane = t & 63, wave = t >> 6;
  int ln = lane & 15, hi = lane >> 4;
  int wr = wave >> 1, wc = wave & 1;

  f32x4 acc[4][4] = {};
  kloop128<false>(A, Bt, m0, n0, As, Bs, t, acc);

#pragma unroll
  for (int i = 0; i < 4; ++i) {
    int mrow = m0 + wr * 64 + i * 16 + hi * 4;
#pragma unroll
    for (int j = 0; j < 4; ++j) {
      int cv = n0 - 1536 + wc * 64 + j * 16 + ln;
      int h = cv >> 6, d = cv & 63;
      int hf = d >> 5, lqd = d & 31;
      float vb = vbias[cv];
#pragma unroll
      for (int r = 0; r < 4; ++r) {
        int mr = mrow + r;
        if (mr < MTOT) {
          int b = mr / NTOK;
          int n = mr - b * NTOK;
          size_t idx = ((((size_t)(h * 8 + b) * 17 + (n >> 6)) * 4 + ((n >> 4) & 3)) * 2 + hf) * 512
                     + (size_t)((((n >> 3) & 1) * 32 + lqd) * 8 + (n & 7));
          vfr[idx] = f2bf(acc[i][j][r] + vb);
        }
      }
    }
  }
}

// ---------------- K3: flash attention — barrier-free, fragment-ready coalesced loads ----------------
// q: [12][MPAD][64] ; kfrag/vfrag as above ; y: [8200][768] bf16
__global__ __launch_bounds__(256) void flash_attn(
    const u16* __restrict__ q, const u16* __restrict__ kfr,
    const u16* __restrict__ vfr, u16* __restrict__ y) {
  int f = blockIdx.x;                 // 864 = 8 XCD-chunks * 108
  int xcd = f & 7, idx = f >> 3;
  int bh = xcd * 12 + idx / 9;
  int qt = idx - (idx / 9) * 9;
  int b = bh / 12, h = bh - b * 12;
  int t = threadIdx.x, lane = t & 63, w = t >> 6;
  int lq = lane & 31, h2 = lane >> 5;
  int q0 = qt * 128 + w * 32;
  if (q0 >= NTOK) return;             // wave-uniform; no barriers in this kernel
  int qrow = q0 + lq; if (qrow > NTOK - 1) qrow = NTOK - 1;

  const u16* qp = q + ((size_t)(h * MPAD) + (size_t)b * NTOK + qrow) * 64;
  bf16x8 qf[4];
#pragma unroll
  for (int s = 0; s < 4; ++s)
    qf[s] = *(const bf16x8*)&qp[s * 16 + h2 * 8];

  const u16* kb = kfr + (size_t)(h * 8 + b) * 34 * 2048 + lane * 8;  // tile stride 4*512
  const u16* vb = vfr + (size_t)(h * 8 + b) * 17 * 4096 + lane * 8;  // tile stride 8*512

  f32x16 acc[2] = {};
  float l = 0.f;

  for (int it = 0; it < 17; ++it) {
    // ---- QK^T (swapped): S^T[key][q]; coalesced fragment loads ----
    f32x16 sc[2] = {};
    __builtin_amdgcn_s_setprio(1);
#pragma unroll
    for (int c = 0; c < 2; ++c) {
      const u16* kp2 = kb + (size_t)(it * 2 + c) * 2048;
#pragma unroll
      for (int s = 0; s < 4; ++s) {
        bf16x8 kf = *(const bf16x8*)(kp2 + s * 512);
        sc[c] = __builtin_amdgcn_mfma_f32_32x32x16_bf16(kf, qf[s], sc[c], 0, 0, 0);
      }
    }
    __builtin_amdgcn_s_setprio(0);
    // ---- no-max softmax: p = exp2(s) ----
    float p[2][16];
#pragma unroll
    for (int c = 0; c < 2; ++c)
#pragma unroll
      for (int r = 0; r < 16; ++r)
        p[c][r] = __builtin_amdgcn_exp2f(sc[c][r]);
    if (it == 16) {                   // zero padded keys (>=1025); overrides garbage
#pragma unroll
      for (int c = 0; c < 2; ++c)
#pragma unroll
        for (int r = 0; r < 16; ++r) {
          int kk = it * 64 + c * 32 + (r & 3) + 8 * (r >> 2) + 4 * h2;
          if (kk >= NTOK) p[c][r] = 0.f;
        }
    }
    float rs = 0.f;
#pragma unroll
    for (int c = 0; c < 2; ++c)
#pragma unroll
      for (int r = 0; r < 16; ++r) rs += p[c][r];
    l += rs;
    // ---- P -> bf16 B-fragments via cvt_pk + v_permlane32_swap_b32 (r9-verified) ----
    bf16x8 frag[4];
#pragma unroll
    for (int c = 0; c < 2; ++c) {
      u32 k0 = cvtpk(p[c][0], p[c][1]),  k1 = cvtpk(p[c][2], p[c][3]);
      u32 k2 = cvtpk(p[c][4], p[c][5]),  k3 = cvtpk(p[c][6], p[c][7]);
      u32 k4 = cvtpk(p[c][8], p[c][9]),  k5 = cvtpk(p[c][10], p[c][11]);
      u32 k6 = cvtpk(p[c][12], p[c][13]), k7 = cvtpk(p[c][14], p[c][15]);
      asm("v_permlane32_swap_b32 %0, %1" : "+v"(k0), "+v"(k2));
      asm("v_permlane32_swap_b32 %0, %1" : "+v"(k1), "+v"(k3));
      asm("v_permlane32_swap_b32 %0, %1" : "+v"(k4), "+v"(k6));
      asm("v_permlane32_swap_b32 %0, %1" : "+v"(k5), "+v"(k7));
      union { u32 u[4]; bf16x8 v; } u0, u1;
      u0.u[0] = k0; u0.u[1] = k1; u0.u[2] = k2; u0.u[3] = k3;
      u1.u[0] = k4; u1.u[1] = k5; u1.u[2] = k6; u1.u[3] = k7;
      frag[c * 2] = u0.v; frag[c * 2 + 1] = u1.v;
    }
    // ---- PV (swapped): Y^T[d][q] += V^T x P; coalesced fragment loads ----
    __builtin_amdgcn_s_setprio(1);
    const u16* vp2 = vb + (size_t)it * 4096;
#pragma unroll
    for (int hf = 0; hf < 2; ++hf) {
#pragma unroll
      for (int s = 0; s < 4; ++s) {
        bf16x8 vf = *(const bf16x8*)(vp2 + (s * 2 + hf) * 512);
        acc[hf] = __builtin_amdgcn_mfma_f32_32x32x16_bf16(vf, frag[s], acc[hf], 0, 0, 0);
      }
    }
    __builtin_amdgcn_s_setprio(0);
  }

  int row = q0 + lq;
  if (row < NTOK) {
    float lt = l + __shfl_xor(l, 32, 64);
    float inv = 1.f / lt;
    u16* yr = y + ((size_t)(b * NTOK + row)) * CDIM + h * 64;
#pragma unroll
    for (int hf = 0; hf < 2; ++hf)
#pragma unroll
      for (int g = 0; g < 4; ++g) {
        int d0 = hf * 32 + 8 * g + 4 * h2;
        ushort4 o;
        o.x = f2bf(acc[hf][g * 4 + 0] * inv);
        o.y = f2bf(acc[hf][g * 4 + 1] * inv);
        o.z = f2bf(acc[hf][g * 4 + 2] * inv);
        o.w = f2bf(acc[hf][g * 4 + 3] * inv);
        *(ushort4*)&yr[d0] = o;
      }
  }
}

// ---------------- K4: LayerNorm (bf16 in) -> bf16 ----------------
__global__ __launch_bounds__(256) void lnorm(const u16* __restrict__ y,
                                             const float* __restrict__ gamma,
                                             const float* __restrict__ beta,
                                             u16* __restrict__ out) {
  int row = blockIdx.x;
  const u16* yr = y + (size_t)row * CDIM;
  int t = threadIdx.x;
  float v[3];
  float s = 0.f, s2 = 0.f;
#pragma unroll
  for (int i = 0; i < 3; ++i) {
    v[i] = bf2f(yr[t + 256 * i]);
    s += v[i]; s2 += v[i] * v[i];
  }
#pragma unroll
  for (int msk = 1; msk < 64; msk <<= 1) {
    s  += __shfl_xor(s, msk, 64);
    s2 += __shfl_xor(s2, msk, 64);
  }
  __shared__ float ws[8];
  int w = t >> 6, lane = t & 63;
  if (lane == 0) { ws[w] = s; ws[4 + w] = s2; }
  __syncthreads();
  s = ws[0] + ws[1] + ws[2] + ws[3];
  s2 = ws[4] + ws[5] + ws[6] + ws[7];
  float mu = s * (1.f / 768.f);
  float var = s2 * (1.f / 768.f) - mu * mu;
  float rstd = rsqrtf(var + 1e-6f);
#pragma unroll
  for (int i = 0; i < 3; ++i) {
    int c = t + 256 * i;
    out[(size_t)row * CDIM + c] = f2bf((v[i] - mu) * rstd * gamma[c] + beta[c]);
  }
}

// ---------------- K5: proj GEMM (transposed frags) + bias -> fp32, float4 stores ----------------
__global__ __launch_bounds__(256) void proj_gemm(
    const u16* __restrict__ A, const u16* __restrict__ Bt,
    const float* __restrict__ bias, float* __restrict__ out) {
  const int NB = 6;
  __shared__ u16 As[8192], Bs[8192];
  int tau0 = blockIdx.x;
  int xcd = tau0 & 7, pos = tau0 >> 3;
  int tau = (xcd < 6) ? xcd * 49 + pos : 294 + (xcd - 6) * 48 + pos;
  int bx = tau % NB, by = tau / NB;
  int m0 = by * 128, n0 = bx * 128;
  int t = threadIdx.x;
  int lane = t & 63, wave = t >> 6;
  int ln = lane & 15, hi = lane >> 4;
  int wr = wave >> 1, wc = wave & 1;

  f32x4 acc[4][4] = {};
  kloop128<true>(A, Bt, m0, n0, As, Bs, t, acc);

#pragma unroll
  for (int ii = 0; ii < 4; ++ii) {
    int m = m0 + wr * 64 + ii * 16 + ln;
    if (m < MTOT) {
      float* dr = out + (size_t)m * CDIM;
#pragma unroll
      for (int jj = 0; jj < 4; ++jj) {
        int c4 = n0 + wc * 64 + jj * 16 + hi * 4;
        float4 bv = *(const float4*)(bias + c4);
        float4 o;
        o.x = acc[jj][ii][0] + bv.x;
        o.y = acc[jj][ii][1] + bv.y;
        o.z = acc[jj][ii][2] + bv.z;
        o.w = acc[jj][ii][3] + bv.w;
        *(float4*)(dr + c4) = o;
      }
    }
  }
}

extern "C" void kernel_launch(void* const* d_in, const int* in_sizes, int n_in,
                              void* d_out, int out_size, void* d_ws, size_t ws_size,
                              hipStream_t stream) {
  const float* x      = (const float*)d_in[0];
  const float* rope   = (const float*)d_in[1];
  const float* w_qkv  = (const float*)d_in[2];
  const float* q_bias = (const float*)d_in[3];
  const float* v_bias = (const float*)d_in[4];
  const float* gamma  = (const float*)d_in[5];
  const float* beta   = (const float*)d_in[6];
  const float* w_proj = (const float*)d_in[7];
  const float* b_proj = (const float*)d_in[8];
  float* out = (float*)d_out;

  // Workspace (57.0 MB):
  //  [0, 12.60M):        xb -> ybf
  //  [12.60M, 16.13M):   wqkvt
  //  [16.13M, 17.31M):   wprjt
  //  [17.31M, 30.29M):   qbuf [12][8448][64] -> ylb
  //  [30.29M, 43.66M):   kfrag [96][34][4][64][8]
  //  [43.66M, 57.03M):   vfrag [96][17][4][2][64][8]
  char* ws = (char*)d_ws;
  u16* xb    = (u16*)(ws);
  u16* ybf   = (u16*)(ws);
  u16* wqkvt = (u16*)(ws + 12595200);
  u16* wprjt = (u16*)(ws + 16134144);
  u16* qbuf  = (u16*)(ws + 17313792);
  u16* ylb   = (u16*)(ws + 17313792);
  u16* kfr   = (u16*)(ws + 30289920);
  u16* vfr   = (u16*)(ws + 43659264);

  conv_x<<<(1574400 + 255) / 256, 256, 0, stream>>>((const float4*)x, xb, 1574400);
  transp<<<dim3(2304 / 32, 768 / 32), 256, 0, stream>>>(w_qkv, wqkvt, 768, 2304);
  transp<<<dim3(768 / 32, 768 / 32), 256, 0, stream>>>(w_proj, wprjt, 768, 768);

  qkv_gemm_t<<<dim3(780), 256, 0, stream>>>(xb, wqkvt, q_bias, rope, qbuf, kfr);
  qkv_gemm_v<<<dim3(390), 256, 0, stream>>>(xb, wqkvt, v_bias, vfr);
  flash_attn<<<dim3(864), 256, 0, stream>>>(qbuf, kfr, vfr, ybf);
  lnorm<<<8200, 256, 0, stream>>>(ybf, gamma, beta, ylb);
  proj_gemm<<<dim3(390), 256, 0, stream>>>(ylb, wprjt, b_proj, out);
}

// Round 11
// 164.899 us; speedup vs baseline: 2.3458x; 1.2348x over previous
//
#include <hip/hip_runtime.h>

typedef __bf16 bf16_t;
typedef __bf16 bf16x8 __attribute__((ext_vector_type(8)));
typedef float f32x4 __attribute__((ext_vector_type(4)));
typedef float f32x16 __attribute__((ext_vector_type(16)));
typedef unsigned short u16;
typedef unsigned int u32;

#define NTOK 1025
#define MTOT 8200
#define MPAD 8448
#define CDIM 768

__device__ __forceinline__ u16 f2bf(float f) {
  union { float f; unsigned u; } v; v.f = f;
  unsigned r = v.u + 0x7fffu + ((v.u >> 16) & 1u);
  return (u16)(r >> 16);
}
__device__ __forceinline__ float bf2f(u16 h) {
  union { unsigned u; float f; } v; v.u = ((unsigned)h) << 16; return v.f;
}
__device__ __forceinline__ u32 cvtpk(float lo, float hi) {
  u32 r; asm("v_cvt_pk_bf16_f32 %0, %1, %2" : "=v"(r) : "v"(lo), "v"(hi)); return r;
}
__device__ __forceinline__ void gld16(const void* g, void* l) {
  __builtin_amdgcn_global_load_lds(
      (const __attribute__((address_space(1))) unsigned*)g,
      (__attribute__((address_space(3))) unsigned*)l, 16, 0, 0);
}

// ---------------- K0a: fp32 -> bf16 convert ----------------
__global__ void conv_x(const float4* __restrict__ in, u16* __restrict__ out, int n4) {
  int i = blockIdx.x * blockDim.x + threadIdx.x;
  if (i < n4) {
    float4 f = in[i];
    ushort4 o; o.x = f2bf(f.x); o.y = f2bf(f.y); o.z = f2bf(f.z); o.w = f2bf(f.w);
    *(ushort4*)&out[i * 4] = o;
  }
}

// ---------------- K0b: transpose-convert  in[K][N] fp32 -> out[N][K] bf16 ----------------
__global__ __launch_bounds__(256) void transp(const float* __restrict__ in,
                                              u16* __restrict__ out, int K, int N) {
  __shared__ float tile[32][33];
  int n0 = blockIdx.x * 32, k0 = blockIdx.y * 32;
  int tx = threadIdx.x & 31, ty = threadIdx.x >> 5;
#pragma unroll
  for (int i = 0; i < 4; ++i)
    tile[ty + i * 8][tx] = in[(k0 + ty + i * 8) * N + n0 + tx];
  __syncthreads();
#pragma unroll
  for (int i = 0; i < 4; ++i)
    out[(n0 + ty + i * 8) * K + k0 + tx] = f2bf(tile[tx][ty + i * 8]);
}

// ---------------- shared 128x128 K-loop (single-buffer, swizzled, r4-proven) ----------------
template <bool TRANS>
__device__ __forceinline__ void kloop128(const u16* __restrict__ A, const u16* __restrict__ Bt,
                                         int m0, int n0, u16* As, u16* Bs, int t,
                                         f32x4 (*acc)[4]) {
  const int K = 768;
  int lane = t & 63, wave = t >> 6;
  int ln = lane & 15, hi = lane >> 4;
  int wr = wave >> 1, wc = wave & 1;
  int swz = (ln & 7) << 4;
  int trow = t >> 3;
  int tcolb = (t & 7) * 16;
  int scol = ((tcolb ^ ((trow & 7) << 4)) >> 1);

  for (int k0 = 0; k0 < K; k0 += 64) {
#pragma unroll
    for (int c = 0; c < 4; ++c) {
      gld16(&A[(size_t)(m0 + c * 32 + trow) * K + k0 + scol], &As[c * 2048 + t * 8]);
      gld16(&Bt[(size_t)(n0 + c * 32 + trow) * K + k0 + scol], &Bs[c * 2048 + t * 8]);
    }
    asm volatile("s_waitcnt vmcnt(0)" ::: "memory");
    __builtin_amdgcn_s_barrier();
    asm volatile("" ::: "memory");
#pragma unroll
    for (int kk = 0; kk < 2; ++kk) {
      bf16x8 af[4], bfr[4];
#pragma unroll
      for (int i = 0; i < 4; ++i)
        af[i] = *(const bf16x8*)((const char*)&As[(wr * 64 + i * 16 + ln) * 64]
                                 + ((kk * 64 + hi * 16) ^ swz));
#pragma unroll
      for (int j = 0; j < 4; ++j)
        bfr[j] = *(const bf16x8*)((const char*)&Bs[(wc * 64 + j * 16 + ln) * 64]
                                  + ((kk * 64 + hi * 16) ^ swz));
      __builtin_amdgcn_s_setprio(1);
#pragma unroll
      for (int x = 0; x < 4; ++x)
#pragma unroll
        for (int y = 0; y < 4; ++y)
          acc[x][y] = TRANS
              ? __builtin_amdgcn_mfma_f32_16x16x32_bf16(bfr[x], af[y], acc[x][y], 0, 0, 0)
              : __builtin_amdgcn_mfma_f32_16x16x32_bf16(af[x], bfr[y], acc[x][y], 0, 0, 0);
      __builtin_amdgcn_s_setprio(0);
    }
    asm volatile("" ::: "memory");
    __builtin_amdgcn_s_barrier();
  }
}

// ---------------- K1a: QKV GEMM q/k cols + bias + RoPE; q plain, k -> fragment layout ----------------
// q: [12][MPAD][64] ; kfrag: [h*8+b][34 tiles][4 s][64 lane][8]
__global__ __launch_bounds__(256) void qkv_gemm_t(
    const u16* __restrict__ A, const u16* __restrict__ Bt,
    const float* __restrict__ qbias, const float* __restrict__ rope,
    u16* __restrict__ q, u16* __restrict__ kfr) {
  const int NB = 12;
  __shared__ u16 As[8192], Bs[8192];
  int tau0 = blockIdx.x;
  int xcd = tau0 & 7, pos = tau0 >> 3;
  int tau = (xcd < 4) ? xcd * 98 + pos : 392 + (xcd - 4) * 97 + pos;
  int bx = tau % NB, by = tau / NB;
  int m0 = by * 128, n0 = bx * 128;
  int t = threadIdx.x;
  int lane = t & 63, wave = t >> 6;
  int ln = lane & 15, hi = lane >> 4;
  int wr = wave >> 1, wc = wave & 1;

  f32x4 acc[4][4] = {};
  kloop128<true>(A, Bt, m0, n0, As, Bs, t, acc);

  const float scale = 0.125f * 1.4426950408889634f;
#pragma unroll
  for (int ii = 0; ii < 4; ++ii) {
    int m = m0 + wr * 64 + ii * 16 + ln;
    if (m < MTOT) {
      int b = m / NTOK;
      int n = m - b * NTOK;
      const float* rp = rope + (size_t)(n - 1) * 128;
#pragma unroll
      for (int jj = 0; jj < 4; ++jj) {
        int c4 = n0 + wc * 64 + jj * 16 + hi * 4;
        int part = (c4 >= CDIM) ? 1 : 0;
        int cc = c4 - part * CDIM;
        int h = cc >> 6, d4 = cc & 63;
        float v0 = acc[jj][ii][0], v1 = acc[jj][ii][1];
        float v2 = acc[jj][ii][2], v3 = acc[jj][ii][3];
        if (part == 0) {
          float4 qb = *(const float4*)(qbias + cc);
          v0 += qb.x; v1 += qb.y; v2 += qb.z; v3 += qb.w;
        }
        float o0, o1, o2, o3;
        if (n > 0) {
          float4 sn = *(const float4*)(rp + d4);
          float4 cs = *(const float4*)(rp + 64 + d4);
          o0 = v0 * cs.x - v1 * sn.x;
          o1 = v1 * cs.y + v0 * sn.y;
          o2 = v2 * cs.z - v3 * sn.z;
          o3 = v3 * cs.w + v2 * sn.w;
        } else { o0 = v0; o1 = v1; o2 = v2; o3 = v3; }
        uint2 w;
        if (part == 0) {
          w.x = cvtpk(o0 * scale, o1 * scale); w.y = cvtpk(o2 * scale, o3 * scale);
          *(uint2*)(q + ((size_t)(h * MPAD + m)) * 64 + d4) = w;
        } else {
          w.x = cvtpk(o0, o1); w.y = cvtpk(o2, o3);
          int kt2 = n >> 5, lqn = n & 31;
          int sF = d4 >> 4, h2d = (d4 >> 3) & 1, j0 = d4 & 7;
          u16* dst = kfr + ((((size_t)(h * 8 + b) * 34 + kt2) * 4 + sF) * 64
                            + h2d * 32 + lqn) * 8 + j0;
          *(uint2*)dst = w;
        }
      }
    }
  }
}

// ---------------- K1b: QKV GEMM v cols + bias -> V fragment layout ----------------
// vfrag: [h*8+b][17 tiles][4 s][2 hf][64 lane][8]
__global__ __launch_bounds__(256) void qkv_gemm_v(
    const u16* __restrict__ A, const u16* __restrict__ Bt,
    const float* __restrict__ vbias, u16* __restrict__ vfr) {
  const int NB = 6;
  __shared__ u16 As[8192], Bs[8192];
  int tau0 = blockIdx.x;
  int xcd = tau0 & 7, pos = tau0 >> 3;
  int tau = (xcd < 6) ? xcd * 49 + pos : 294 + (xcd - 6) * 48 + pos;
  int bx = tau % NB, by = tau / NB;
  int m0 = by * 128, n0 = 1536 + bx * 128;
  int t = threadIdx.x;
  int lane = t & 63, wave = t >> 6;
  int ln = lane & 15, hi = lane >> 4;
  int wr = wave >> 1, wc = wave & 1;

  f32x4 acc[4][4] = {};
  kloop128<false>(A, Bt, m0, n0, As, Bs, t, acc);

#pragma unroll
  for (int i = 0; i < 4; ++i) {
    int mrow = m0 + wr * 64 + i * 16 + hi * 4;
#pragma unroll
    for (int j = 0; j < 4; ++j) {
      int cv = n0 - 1536 + wc * 64 + j * 16 + ln;
      int h = cv >> 6, d = cv & 63;
      int hf = d >> 5, lqd = d & 31;
      float vb = vbias[cv];
#pragma unroll
      for (int r = 0; r < 4; ++r) {
        int mr = mrow + r;
        if (mr < MTOT) {
          int b = mr / NTOK;
          int n = mr - b * NTOK;
          size_t idx = ((((size_t)(h * 8 + b) * 17 + (n >> 6)) * 4 + ((n >> 4) & 3)) * 2 + hf) * 512
                     + (size_t)((((n >> 3) & 1) * 32 + lqd) * 8 + (n & 7));
          vfr[idx] = f2bf(acc[i][j][r] + vb);
        }
      }
    }
  }
}

// ---------------- flash iteration body: prefetch-K + in-iter V + compute ----------------
template <bool PF, bool MASK>
__device__ __forceinline__ void flash_iter(
    bf16x8 (&kf)[8], bf16x8 (&kn)[8], int pftile, int it,
    const u16* kfb, const u16* vfb, int h2,
    const bf16x8 (&qf)[4], f32x16 (&acc)[2], float& l) {
  // 1) issue next-tile K loads (full iteration of flight time)
  if (PF) {
    const u16* kp2 = kfb + (size_t)pftile * 4096;
#pragma unroll
    for (int c = 0; c < 2; ++c)
#pragma unroll
      for (int s = 0; s < 4; ++s)
        kn[c * 4 + s] = *(const bf16x8*)(kp2 + c * 2048 + s * 512);
  }
  // 2) issue current-tile V loads (consumed after softmax, ~300+ cyc away)
  bf16x8 vf[8];
  const u16* vp2 = vfb + (size_t)it * 4096;
#pragma unroll
  for (int hf = 0; hf < 2; ++hf)
#pragma unroll
    for (int s = 0; s < 4; ++s)
      vf[hf * 4 + s] = *(const bf16x8*)(vp2 + (s * 2 + hf) * 512);
  // 3) QK^T (swapped): S^T[key][q]
  f32x16 sc[2] = {};
  __builtin_amdgcn_s_setprio(1);
#pragma unroll
  for (int c = 0; c < 2; ++c)
#pragma unroll
    for (int s = 0; s < 4; ++s)
      sc[c] = __builtin_amdgcn_mfma_f32_32x32x16_bf16(kf[c * 4 + s], qf[s], sc[c], 0, 0, 0);
  __builtin_amdgcn_s_setprio(0);
  // 4) no-max softmax in place: p = exp2(s)
#pragma unroll
  for (int c = 0; c < 2; ++c)
#pragma unroll
    for (int r = 0; r < 16; ++r)
      sc[c][r] = __builtin_amdgcn_exp2f(sc[c][r]);
  if (MASK) {
#pragma unroll
    for (int c = 0; c < 2; ++c)
#pragma unroll
      for (int r = 0; r < 16; ++r) {
        int kk = it * 64 + c * 32 + (r & 3) + 8 * (r >> 2) + 4 * h2;
        if (kk >= NTOK) sc[c][r] = 0.f;
      }
  }
  float rs = 0.f;
#pragma unroll
  for (int c = 0; c < 2; ++c)
#pragma unroll
    for (int r = 0; r < 16; ++r) rs += sc[c][r];
  l += rs;
  // 5) P -> bf16 B-fragments via cvt_pk + v_permlane32_swap_b32 (r9-verified order)
  bf16x8 frag[4];
#pragma unroll
  for (int c = 0; c < 2; ++c) {
    u32 k0 = cvtpk(sc[c][0], sc[c][1]),   k1 = cvtpk(sc[c][2], sc[c][3]);
    u32 k2 = cvtpk(sc[c][4], sc[c][5]),   k3 = cvtpk(sc[c][6], sc[c][7]);
    u32 k4 = cvtpk(sc[c][8], sc[c][9]),   k5 = cvtpk(sc[c][10], sc[c][11]);
    u32 k6 = cvtpk(sc[c][12], sc[c][13]), k7 = cvtpk(sc[c][14], sc[c][15]);
    asm("v_permlane32_swap_b32 %0, %1" : "+v"(k0), "+v"(k2));
    asm("v_permlane32_swap_b32 %0, %1" : "+v"(k1), "+v"(k3));
    asm("v_permlane32_swap_b32 %0, %1" : "+v"(k4), "+v"(k6));
    asm("v_permlane32_swap_b32 %0, %1" : "+v"(k5), "+v"(k7));
    union { u32 u[4]; bf16x8 v; } u0, u1;
    u0.u[0] = k0; u0.u[1] = k1; u0.u[2] = k2; u0.u[3] = k3;
    u1.u[0] = k4; u1.u[1] = k5; u1.u[2] = k6; u1.u[3] = k7;
    frag[c * 2] = u0.v; frag[c * 2 + 1] = u1.v;
  }
  // 6) PV (swapped): Y^T[d][q] += V^T x P
  __builtin_amdgcn_s_setprio(1);
#pragma unroll
  for (int hf = 0; hf < 2; ++hf)
#pragma unroll
    for (int s = 0; s < 4; ++s)
      acc[hf] = __builtin_amdgcn_mfma_f32_32x32x16_bf16(vf[hf * 4 + s], frag[s], acc[hf], 0, 0, 0);
  __builtin_amdgcn_s_setprio(0);
}

// ---------------- K3: flash attention — barrier-free, register-prefetched (T14) ----------------
// q: [12][MPAD][64] ; kfrag/vfrag as above ; y: [8200][768] bf16
__global__ __launch_bounds__(256, 2) void flash_attn(
    const u16* __restrict__ q, const u16* __restrict__ kfr,
    const u16* __restrict__ vfr, u16* __restrict__ y) {
  int f = blockIdx.x;                 // 864 = 8 XCD-chunks * 108
  int xcd = f & 7, idx = f >> 3;
  int bh = xcd * 12 + idx / 9;
  int qt = idx - (idx / 9) * 9;
  int b = bh / 12, h = bh - b * 12;
  int t = threadIdx.x, lane = t & 63, w = t >> 6;
  int lq = lane & 31, h2 = lane >> 5;
  int q0 = qt * 128 + w * 32;
  if (q0 >= NTOK) return;             // wave-uniform; no barriers in this kernel
  int qrow = q0 + lq; if (qrow > NTOK - 1) qrow = NTOK - 1;

  const u16* qp = q + ((size_t)(h * MPAD) + (size_t)b * NTOK + qrow) * 64;
  bf16x8 qf[4];
#pragma unroll
  for (int s = 0; s < 4; ++s)
    qf[s] = *(const bf16x8*)&qp[s * 16 + h2 * 8];

  const u16* kfb = kfr + (size_t)(h * 8 + b) * 34 * 2048 + lane * 8;
  const u16* vfb = vfr + (size_t)(h * 8 + b) * 17 * 4096 + lane * 8;

  f32x16 acc[2] = {};
  float l = 0.f;

  // prologue: K tile 0 into ka
  bf16x8 ka[8], kb2[8];
#pragma unroll
  for (int c = 0; c < 2; ++c)
#pragma unroll
    for (int s = 0; s < 4; ++s)
      ka[c * 4 + s] = *(const bf16x8*)(kfb + c * 2048 + s * 512);

#pragma unroll 1
  for (int i2 = 0; i2 < 8; ++i2) {
    flash_iter<true, false>(ka, kb2, 2 * i2 + 1, 2 * i2, kfb, vfb, h2, qf, acc, l);
    flash_iter<true, false>(kb2, ka, 2 * i2 + 2, 2 * i2 + 1, kfb, vfb, h2, qf, acc, l);
  }
  flash_iter<false, true>(ka, kb2, 0, 16, kfb, vfb, h2, qf, acc, l);

  int row = q0 + lq;
  if (row < NTOK) {
    float lt = l + __shfl_xor(l, 32, 64);
    float inv = 1.f / lt;
    u16* yr = y + ((size_t)(b * NTOK + row)) * CDIM + h * 64;
#pragma unroll
    for (int hf = 0; hf < 2; ++hf)
#pragma unroll
      for (int g = 0; g < 4; ++g) {
        int d0 = hf * 32 + 8 * g + 4 * h2;
        ushort4 o;
        o.x = f2bf(acc[hf][g * 4 + 0] * inv);
        o.y = f2bf(acc[hf][g * 4 + 1] * inv);
        o.z = f2bf(acc[hf][g * 4 + 2] * inv);
        o.w = f2bf(acc[hf][g * 4 + 3] * inv);
        *(ushort4*)&yr[d0] = o;
      }
  }
}

// ---------------- K4: LayerNorm (bf16 in) -> bf16 ----------------
__global__ __launch_bounds__(256) void lnorm(const u16* __restrict__ y,
                                             const float* __restrict__ gamma,
                                             const float* __restrict__ beta,
                                             u16* __restrict__ out) {
  int row = blockIdx.x;
  const u16* yr = y + (size_t)row * CDIM;
  int t = threadIdx.x;
  float v[3];
  float s = 0.f, s2 = 0.f;
#pragma unroll
  for (int i = 0; i < 3; ++i) {
    v[i] = bf2f(yr[t + 256 * i]);
    s += v[i]; s2 += v[i] * v[i];
  }
#pragma unroll
  for (int msk = 1; msk < 64; msk <<= 1) {
    s  += __shfl_xor(s, msk, 64);
    s2 += __shfl_xor(s2, msk, 64);
  }
  __shared__ float ws[8];
  int w = t >> 6, lane = t & 63;
  if (lane == 0) { ws[w] = s; ws[4 + w] = s2; }
  __syncthreads();
  s = ws[0] + ws[1] + ws[2] + ws[3];
  s2 = ws[4] + ws[5] + ws[6] + ws[7];
  float mu = s * (1.f / 768.f);
  float var = s2 * (1.f / 768.f) - mu * mu;
  float rstd = rsqrtf(var + 1e-6f);
#pragma unroll
  for (int i = 0; i < 3; ++i) {
    int c = t + 256 * i;
    out[(size_t)row * CDIM + c] = f2bf((v[i] - mu) * rstd * gamma[c] + beta[c]);
  }
}

// ---------------- K5: proj GEMM (transposed frags) + bias -> fp32, float4 stores ----------------
__global__ __launch_bounds__(256) void proj_gemm(
    const u16* __restrict__ A, const u16* __restrict__ Bt,
    const float* __restrict__ bias, float* __restrict__ out) {
  const int NB = 6;
  __shared__ u16 As[8192], Bs[8192];
  int tau0 = blockIdx.x;
  int xcd = tau0 & 7, pos = tau0 >> 3;
  int tau = (xcd < 6) ? xcd * 49 + pos : 294 + (xcd - 6) * 48 + pos;
  int bx = tau % NB, by = tau / NB;
  int m0 = by * 128, n0 = bx * 128;
  int t = threadIdx.x;
  int lane = t & 63, wave = t >> 6;
  int ln = lane & 15, hi = lane >> 4;
  int wr = wave >> 1, wc = wave & 1;

  f32x4 acc[4][4] = {};
  kloop128<true>(A, Bt, m0, n0, As, Bs, t, acc);

#pragma unroll
  for (int ii = 0; ii < 4; ++ii) {
    int m = m0 + wr * 64 + ii * 16 + ln;
    if (m < MTOT) {
      float* dr = out + (size_t)m * CDIM;
#pragma unroll
      for (int jj = 0; jj < 4; ++jj) {
        int c4 = n0 + wc * 64 + jj * 16 + hi * 4;
        float4 bv = *(const float4*)(bias + c4);
        float4 o;
        o.x = acc[jj][ii][0] + bv.x;
        o.y = acc[jj][ii][1] + bv.y;
        o.z = acc[jj][ii][2] + bv.z;
        o.w = acc[jj][ii][3] + bv.w;
        *(float4*)(dr + c4) = o;
      }
    }
  }
}

extern "C" void kernel_launch(void* const* d_in, const int* in_sizes, int n_in,
                              void* d_out, int out_size, void* d_ws, size_t ws_size,
                              hipStream_t stream) {
  const float* x      = (const float*)d_in[0];
  const float* rope   = (const float*)d_in[1];
  const float* w_qkv  = (const float*)d_in[2];
  const float* q_bias = (const float*)d_in[3];
  const float* v_bias = (const float*)d_in[4];
  const float* gamma  = (const float*)d_in[5];
  const float* beta   = (const float*)d_in[6];
  const float* w_proj = (const float*)d_in[7];
  const float* b_proj = (const float*)d_in[8];
  float* out = (float*)d_out;

  // Workspace (57.0 MB):
  //  [0, 12.60M):        xb -> ybf
  //  [12.60M, 16.13M):   wqkvt
  //  [16.13M, 17.31M):   wprjt
  //  [17.31M, 30.29M):   qbuf [12][8448][64] -> ylb
  //  [30.29M, 43.66M):   kfrag [96][34][4][64][8]
  //  [43.66M, 57.03M):   vfrag [96][17][4][2][64][8]
  char* ws = (char*)d_ws;
  u16* xb    = (u16*)(ws);
  u16* ybf   = (u16*)(ws);
  u16* wqkvt = (u16*)(ws + 12595200);
  u16* wprjt = (u16*)(ws + 16134144);
  u16* qbuf  = (u16*)(ws + 17313792);
  u16* ylb   = (u16*)(ws + 17313792);
  u16* kfr   = (u16*)(ws + 30289920);
  u16* vfr   = (u16*)(ws + 43659264);

  conv_x<<<(1574400 + 255) / 256, 256, 0, stream>>>((const float4*)x, xb, 1574400);
  transp<<<dim3(2304 / 32, 768 / 32), 256, 0, stream>>>(w_qkv, wqkvt, 768, 2304);
  transp<<<dim3(768 / 32, 768 / 32), 256, 0, stream>>>(w_proj, wprjt, 768, 768);

  qkv_gemm_t<<<dim3(780), 256, 0, stream>>>(xb, wqkvt, q_bias, rope, qbuf, kfr);
  qkv_gemm_v<<<dim3(390), 256, 0, stream>>>(xb, wqkvt, v_bias, vfr);
  flash_attn<<<dim3(864), 256, 0, stream>>>(qbuf, kfr, vfr, ybf);
  lnorm<<<8200, 256, 0, stream>>>(ybf, gamma, beta, ylb);
  proj_gemm<<<dim3(390), 256, 0, stream>>>(ylb, wprjt, b_proj, out);
}